// Round 1
// baseline (1213.312 us; speedup 1.0000x reference)
//
#include <hip/hip_runtime.h>

#define NH 3
#define HID 8
#define C1 24   // NH*HID
#define C2 16

// ---------------- layer-1 projection: z1[N][24], f1s/f1d[N][4] ----------------
__global__ __launch_bounds__(256) void k_z1(
    const float* __restrict__ emb, const float* __restrict__ W1g,
    const float* __restrict__ a1g, float* __restrict__ z1,
    float4* __restrict__ f1s, float4* __restrict__ f1d, int N) {
    __shared__ float sW[NH * 64 * HID];   // [h][d][o]
    __shared__ float sa[NH * 2 * HID];
    for (int i = threadIdx.x; i < NH * 64 * HID; i += blockDim.x) sW[i] = W1g[i];
    for (int i = threadIdx.x; i < NH * 2 * HID; i += blockDim.x) sa[i] = a1g[i];
    __syncthreads();
    int n = blockIdx.x * blockDim.x + threadIdx.x;
    if (n >= N) return;
    float e[64];
    const float4* ep = (const float4*)(emb + (size_t)n * 64);
#pragma unroll
    for (int i = 0; i < 16; ++i) {
        float4 v = ep[i];
        e[4*i+0] = v.x; e[4*i+1] = v.y; e[4*i+2] = v.z; e[4*i+3] = v.w;
    }
    float z[C1];
#pragma unroll
    for (int c = 0; c < C1; ++c) z[c] = 0.f;
    for (int d = 0; d < 64; ++d) {
        float ed = e[d];
#pragma unroll
        for (int h = 0; h < NH; ++h) {
            const float4* wp = (const float4*)&sW[(h * 64 + d) * HID];
            float4 w0 = wp[0], w1 = wp[1];
            z[h*HID+0] += ed * w0.x; z[h*HID+1] += ed * w0.y;
            z[h*HID+2] += ed * w0.z; z[h*HID+3] += ed * w0.w;
            z[h*HID+4] += ed * w1.x; z[h*HID+5] += ed * w1.y;
            z[h*HID+6] += ed * w1.z; z[h*HID+7] += ed * w1.w;
        }
    }
    float4* zp = (float4*)(z1 + (size_t)n * C1);
#pragma unroll
    for (int i = 0; i < 6; ++i)
        zp[i] = make_float4(z[4*i], z[4*i+1], z[4*i+2], z[4*i+3]);
    float fs[NH], fd[NH];
#pragma unroll
    for (int h = 0; h < NH; ++h) {
        float s = 0.f, dsum = 0.f;
#pragma unroll
        for (int o = 0; o < HID; ++o) {
            s    += z[h*HID+o] * sa[h*2*HID + o];
            dsum += z[h*HID+o] * sa[h*2*HID + HID + o];
        }
        fs[h] = s; fd[h] = dsum;
    }
    f1s[n] = make_float4(fs[0], fs[1], fs[2], 0.f);
    f1d[n] = make_float4(fd[0], fd[1], fd[2], 0.f);
}

// ---------------- CSR build ----------------
__global__ void k_zero(int* __restrict__ p, int n) {
    int i = blockIdx.x * blockDim.x + threadIdx.x;
    if (i < n) p[i] = 0;
}

__global__ void k_hist(const int* __restrict__ dst, int* __restrict__ deg, int E) {
    int e = blockIdx.x * blockDim.x + threadIdx.x;
    if (e < E) atomicAdd(&deg[dst[e]], 1);
}

// chunk = 1024 elements per block (256 threads x 4 consecutive)
__global__ __launch_bounds__(256) void k_scan1(const int* __restrict__ deg,
                                               int* __restrict__ partials, int N) {
    __shared__ int sd[256];
    int tid = threadIdx.x;
    int g0 = blockIdx.x * 1024 + tid * 4;
    int s = 0;
#pragma unroll
    for (int i = 0; i < 4; ++i) { int g = g0 + i; if (g < N) s += deg[g]; }
    sd[tid] = s; __syncthreads();
    for (int off = 128; off; off >>= 1) {
        if (tid < off) sd[tid] += sd[tid + off];
        __syncthreads();
    }
    if (tid == 0) partials[blockIdx.x] = sd[0];
}

__global__ __launch_bounds__(256) void k_scan2(int* __restrict__ partials, int nchunks) {
    __shared__ int sd[256];
    int tid = threadIdx.x;
    int v = (tid < nchunks) ? partials[tid] : 0;
    sd[tid] = v; __syncthreads();
    for (int off = 1; off < 256; off <<= 1) {
        int t = (tid >= off) ? sd[tid - off] : 0;
        __syncthreads();
        sd[tid] += t;
        __syncthreads();
    }
    if (tid < nchunks) partials[tid] = sd[tid] - v;   // exclusive chunk offsets
}

__global__ __launch_bounds__(256) void k_scan3(const int* __restrict__ deg,
                                               const int* __restrict__ partials,
                                               int* __restrict__ rowptr,
                                               int* __restrict__ cursor, int N) {
    __shared__ int sd[256];
    int tid = threadIdx.x;
    int g0 = blockIdx.x * 1024 + tid * 4;
    int v[4];
#pragma unroll
    for (int i = 0; i < 4; ++i) { int g = g0 + i; v[i] = (g < N) ? deg[g] : 0; }
    int tsum = v[0] + v[1] + v[2] + v[3];
    sd[tid] = tsum; __syncthreads();
    for (int off = 1; off < 256; off <<= 1) {
        int t = (tid >= off) ? sd[tid - off] : 0;
        __syncthreads();
        sd[tid] += t;
        __syncthreads();
    }
    int pref = partials[blockIdx.x] + sd[tid] - tsum;
#pragma unroll
    for (int i = 0; i < 4; ++i) {
        int g = g0 + i;
        if (g < N) {
            rowptr[g] = pref;
            cursor[g] = pref;
            if (g == N - 1) rowptr[N] = pref + v[i];
            pref += v[i];
        }
    }
}

__global__ void k_scatter(const int* __restrict__ src, const int* __restrict__ dst,
                          int* __restrict__ cursor, int* __restrict__ csr, int E) {
    int e = blockIdx.x * blockDim.x + threadIdx.x;
    if (e < E) {
        int p = atomicAdd(&cursor[dst[e]], 1);
        csr[p] = src[e];
    }
}

// ---------------- GAT layer 1 aggregate + elu + layer-2 projection ----------------
__global__ __launch_bounds__(256) void k_gat1(
    const int* __restrict__ rowptr, const int* __restrict__ csr,
    const float* __restrict__ z1, const float4* __restrict__ f1s,
    const float4* __restrict__ f1d,
    const float* __restrict__ W2g, const float* __restrict__ a2g,
    float* __restrict__ z2, float* __restrict__ f2s, float* __restrict__ f2d, int N) {
    __shared__ float sW2[C1 * C2];
    __shared__ float sa2[2 * C2];
    for (int i = threadIdx.x; i < C1 * C2; i += blockDim.x) sW2[i] = W2g[i];
    for (int i = threadIdx.x; i < 2 * C2; i += blockDim.x) sa2[i] = a2g[i];
    __syncthreads();
    int n = blockIdx.x * blockDim.x + threadIdx.x;
    if (n >= N) return;
    int beg = rowptr[n], end = rowptr[n + 1];
    float4 fdv = f1d[n];
    float acc[C1];
#pragma unroll
    for (int c = 0; c < C1; ++c) acc[c] = 0.f;
    float den[NH] = {0.f, 0.f, 0.f};
    for (int i = beg; i < end; ++i) {
        int s = csr[i];
        float4 fsv = f1s[s];
        float e0 = fsv.x + fdv.x, e1 = fsv.y + fdv.y, e2 = fsv.z + fdv.z;
        e0 = e0 > 0.f ? e0 : 0.01f * e0;
        e1 = e1 > 0.f ? e1 : 0.01f * e1;
        e2 = e2 > 0.f ? e2 : 0.01f * e2;
        float av[NH];
        av[0] = __expf(e0); av[1] = __expf(e1); av[2] = __expf(e2);
        den[0] += av[0]; den[1] += av[1]; den[2] += av[2];
        const float4* zp = (const float4*)(z1 + (size_t)s * C1);
        float4 q[6];
#pragma unroll
        for (int j = 0; j < 6; ++j) q[j] = zp[j];
#pragma unroll
        for (int h = 0; h < NH; ++h) {
            float a = av[h];
            acc[h*8+0] += a * q[h*2].x;   acc[h*8+1] += a * q[h*2].y;
            acc[h*8+2] += a * q[h*2].z;   acc[h*8+3] += a * q[h*2].w;
            acc[h*8+4] += a * q[h*2+1].x; acc[h*8+5] += a * q[h*2+1].y;
            acc[h*8+6] += a * q[h*2+1].z; acc[h*8+7] += a * q[h*2+1].w;
        }
    }
    float h1v[C1];
#pragma unroll
    for (int h = 0; h < NH; ++h) {
        float inv = 1.f / den[h];
#pragma unroll
        for (int o = 0; o < HID; ++o) {
            float v = acc[h*HID+o] * inv;
            h1v[h*HID+o] = v > 0.f ? v : (__expf(v) - 1.f);
        }
    }
    float zz[C2];
#pragma unroll
    for (int k = 0; k < C2; ++k) zz[k] = 0.f;
    for (int c = 0; c < C1; ++c) {
        float hv = h1v[c];
#pragma unroll
        for (int k = 0; k < C2; ++k) zz[k] += hv * sW2[c*C2 + k];
    }
    float fs = 0.f, fdd = 0.f;
#pragma unroll
    for (int k = 0; k < C2; ++k) {
        fs  += zz[k] * sa2[k];
        fdd += zz[k] * sa2[C2 + k];
    }
    float4* zo = (float4*)(z2 + (size_t)n * C2);
#pragma unroll
    for (int i = 0; i < 4; ++i)
        zo[i] = make_float4(zz[4*i], zz[4*i+1], zz[4*i+2], zz[4*i+3]);
    f2s[n] = fs;
    f2d[n] = fdd;
}

// ---------------- GAT layer 2 aggregate -> item_embeds[N][16] ----------------
__global__ __launch_bounds__(256) void k_gat2(
    const int* __restrict__ rowptr, const int* __restrict__ csr,
    const float* __restrict__ z2, const float* __restrict__ f2s,
    const float* __restrict__ f2d, float* __restrict__ item, int N) {
    int n = blockIdx.x * blockDim.x + threadIdx.x;
    if (n >= N) return;
    int beg = rowptr[n], end = rowptr[n + 1];
    float fdv = f2d[n];
    float acc[C2];
#pragma unroll
    for (int k = 0; k < C2; ++k) acc[k] = 0.f;
    float den = 0.f;
    for (int i = beg; i < end; ++i) {
        int s = csr[i];
        float e = f2s[s] + fdv;
        e = e > 0.f ? e : 0.01f * e;
        float a = __expf(e);
        den += a;
        const float4* zp = (const float4*)(z2 + (size_t)s * C2);
        float4 q0 = zp[0], q1 = zp[1], q2 = zp[2], q3 = zp[3];
        acc[0]  += a * q0.x; acc[1]  += a * q0.y; acc[2]  += a * q0.z; acc[3]  += a * q0.w;
        acc[4]  += a * q1.x; acc[5]  += a * q1.y; acc[6]  += a * q1.z; acc[7]  += a * q1.w;
        acc[8]  += a * q2.x; acc[9]  += a * q2.y; acc[10] += a * q2.z; acc[11] += a * q2.w;
        acc[12] += a * q3.x; acc[13] += a * q3.y; acc[14] += a * q3.z; acc[15] += a * q3.w;
    }
    float inv = 1.f / den;
    float4* io = (float4*)(item + (size_t)n * C2);
#pragma unroll
    for (int i = 0; i < 4; ++i)
        io[i] = make_float4(acc[4*i]*inv, acc[4*i+1]*inv, acc[4*i+2]*inv, acc[4*i+3]*inv);
}

// ---------------- query pooling: one block per query row ----------------
__global__ __launch_bounds__(256) void k_query(
    const float* __restrict__ queries, const float* __restrict__ item,
    float* __restrict__ out, int N) {
    int b = blockIdx.x;
    const float4* qrow = (const float4*)(queries + (size_t)b * N);
    int n4 = N >> 2;
    float acc[C2];
#pragma unroll
    for (int k = 0; k < C2; ++k) acc[k] = 0.f;
    float cnt = 0.f;
    for (int i = threadIdx.x; i < n4; i += 256) {
        float4 v = qrow[i];
        int j = i * 4;
        float vv[4] = {v.x, v.y, v.z, v.w};
#pragma unroll
        for (int c = 0; c < 4; ++c) {
            if (vv[c] != 0.f) {
                cnt += vv[c];
                const float4* rp = (const float4*)(item + (size_t)(j + c) * C2);
                float4 r0 = rp[0], r1 = rp[1], r2 = rp[2], r3 = rp[3];
                acc[0]  += vv[c]*r0.x; acc[1]  += vv[c]*r0.y; acc[2]  += vv[c]*r0.z; acc[3]  += vv[c]*r0.w;
                acc[4]  += vv[c]*r1.x; acc[5]  += vv[c]*r1.y; acc[6]  += vv[c]*r1.z; acc[7]  += vv[c]*r1.w;
                acc[8]  += vv[c]*r2.x; acc[9]  += vv[c]*r2.y; acc[10] += vv[c]*r2.z; acc[11] += vv[c]*r2.w;
                acc[12] += vv[c]*r3.x; acc[13] += vv[c]*r3.y; acc[14] += vv[c]*r3.z; acc[15] += vv[c]*r3.w;
            }
        }
    }
    int rem = N & 3;
    if ((int)threadIdx.x < rem) {
        int j = n4 * 4 + threadIdx.x;
        float qv = queries[(size_t)b * N + j];
        if (qv != 0.f) {
            cnt += qv;
#pragma unroll
            for (int k = 0; k < C2; ++k) acc[k] += qv * item[(size_t)j * C2 + k];
        }
    }
    // reduce across block (4 waves of 64)
    __shared__ float red[4][C2 + 1];
    int lane = threadIdx.x & 63, wid = threadIdx.x >> 6;
#pragma unroll
    for (int k = 0; k < C2; ++k)
        for (int off = 32; off; off >>= 1) acc[k] += __shfl_down(acc[k], off, 64);
    for (int off = 32; off; off >>= 1) cnt += __shfl_down(cnt, off, 64);
    if (lane == 0) {
#pragma unroll
        for (int k = 0; k < C2; ++k) red[wid][k] = acc[k];
        red[wid][C2] = cnt;
    }
    __syncthreads();
    if (threadIdx.x < C2 + 1) {
        float s = red[0][threadIdx.x] + red[1][threadIdx.x] +
                  red[2][threadIdx.x] + red[3][threadIdx.x];
        red[0][threadIdx.x] = s;
    }
    __syncthreads();
    if (threadIdx.x < C2)
        out[(size_t)b * C2 + threadIdx.x] = red[0][threadIdx.x] / red[0][C2];
}

// ---------------- pos/neg gathers ----------------
__global__ void k_posneg(const int* __restrict__ pos, const int* __restrict__ neg,
                         const float* __restrict__ item, float* __restrict__ out, int B) {
    int idx = blockIdx.x * blockDim.x + threadIdx.x;
    int total = 2 * B * C2;
    if (idx >= total) return;
    int which = idx / (B * C2);
    int r = idx - which * B * C2;
    int b = r / C2, k = r - b * C2;
    int node = which ? neg[b] : pos[b];
    out[(size_t)B * C2 + idx] = item[(size_t)node * C2 + k];
}

extern "C" void kernel_launch(void* const* d_in, const int* in_sizes, int n_in,
                              void* d_out, int out_size, void* d_ws, size_t ws_size,
                              hipStream_t stream) {
    const float* queries = (const float*)d_in[0];
    const int*   pos     = (const int*)d_in[1];
    const int*   neg     = (const int*)d_in[2];
    const float* emb     = (const float*)d_in[3];
    const float* W1      = (const float*)d_in[4];
    const float* a1      = (const float*)d_in[5];
    const float* W2      = (const float*)d_in[6];
    const float* a2      = (const float*)d_in[7];
    const int*   src     = (const int*)d_in[8];
    const int*   dst     = (const int*)d_in[9];

    int B = in_sizes[1];
    int N = in_sizes[3] / 64;
    int E = in_sizes[8];
    float* out = (float*)d_out;

    char* w = (char*)d_ws;
    auto alloc = [&](size_t bytes) -> char* {
        char* p = w;
        w += (bytes + 255) & ~(size_t)255;
        return p;
    };
    float*  z1    = (float*)alloc(sizeof(float) * (size_t)N * C1);
    float4* f1s   = (float4*)alloc(sizeof(float4) * (size_t)N);
    float4* f1d   = (float4*)alloc(sizeof(float4) * (size_t)N);
    float*  z2    = (float*)alloc(sizeof(float) * (size_t)N * C2);
    float*  f2s   = (float*)alloc(sizeof(float) * (size_t)N);
    float*  f2d   = (float*)alloc(sizeof(float) * (size_t)N);
    float*  item  = (float*)alloc(sizeof(float) * (size_t)N * C2);
    int*    rowptr= (int*)alloc(sizeof(int) * (size_t)(N + 1));
    int*    cursor= (int*)alloc(sizeof(int) * (size_t)N);
    int*    deg   = (int*)alloc(sizeof(int) * (size_t)N);
    int*    parts = (int*)alloc(sizeof(int) * 256);
    int*    csr   = (int*)alloc(sizeof(int) * (size_t)E);

    int nblkN = (N + 255) / 256;
    int nblkE = (E + 255) / 256;
    int nchunks = (N + 1023) / 1024;

    k_z1<<<nblkN, 256, 0, stream>>>(emb, W1, a1, z1, f1s, f1d, N);
    k_zero<<<nblkN, 256, 0, stream>>>(deg, N);
    k_hist<<<nblkE, 256, 0, stream>>>(dst, deg, E);
    k_scan1<<<nchunks, 256, 0, stream>>>(deg, parts, N);
    k_scan2<<<1, 256, 0, stream>>>(parts, nchunks);
    k_scan3<<<nchunks, 256, 0, stream>>>(deg, parts, rowptr, cursor, N);
    k_scatter<<<nblkE, 256, 0, stream>>>(src, dst, cursor, csr, E);
    k_gat1<<<nblkN, 256, 0, stream>>>(rowptr, csr, z1, f1s, f1d, W2, a2, z2, f2s, f2d, N);
    k_gat2<<<nblkN, 256, 0, stream>>>(rowptr, csr, z2, f2s, f2d, item, N);
    k_query<<<B, 256, 0, stream>>>(queries, item, out, N);
    k_posneg<<<(2 * B * C2 + 255) / 256, 256, 0, stream>>>(pos, neg, item, out, B);
}